// Round 6
// baseline (153.953 us; speedup 1.0000x reference)
//
#include <hip/hip_runtime.h>
#include <cstdint>
#include <cstddef>

// ---------------------------------------------------------------------------
// SelfAttention (b=4, C=64, 128x128) — MFMA bf16, round 6.
// Math as rounds 2-5 (no-max softmax; pi-permuted Vpp/Wop feed MFMA B-operand
// by bitcast). Round-6: Schraudolph fast-exp2 (bit-hack -> bf16 via v_perm),
// k_lsum split 2x over k (8 waves/SIMD, FB=1, partial sums), k_qkv 8-wave
// with transposed-weight broadcast reads, k_attn epilogue x-prefetch.
// ---------------------------------------------------------------------------

#define LOG2E 1.44269504088896340736f
#define FE_A 8388608.0f        // 2^23
#define FE_B 1064993098.0f     // 127*2^23 - 360118 (centers rel err to ±3%)

typedef __attribute__((ext_vector_type(8)))  __bf16 bf8_t;
typedef __attribute__((ext_vector_type(16))) float  fx16;

__device__ __forceinline__ unsigned short f2bf(float f) {
  unsigned int u = __builtin_bit_cast(unsigned int, f);
  u += 0x7FFFu + ((u >> 16) & 1u);   // round-nearest-even
  return (unsigned short)(u >> 16);
}
__device__ __forceinline__ unsigned int pk2(unsigned short lo, unsigned short hi) {
  return (unsigned int)lo | ((unsigned int)hi << 16);
}
// involution permutation on a 16-group: swap middle two quads
__device__ __forceinline__ int pi16(int s) {
  int m = (s >> 2) & 3;
  return (m == 1 || m == 2) ? (s ^ 12) : s;
}
// fast exp2: f32 bits of 2^s ~= s*2^23 + bias (linear-mantissa approx)
__device__ __forceinline__ unsigned fe_u(float s) {
  return (unsigned)fmaf(s, FE_A, FE_B);
}
__device__ __forceinline__ float fe_f(float s) {
  return __builtin_bit_cast(float, fe_u(s));
}
// pack bf16(2^s0), bf16(2^s1) into one dword (hi16 of each f32 pattern)
__device__ __forceinline__ unsigned fe_pk(float s0, float s1) {
  return __builtin_amdgcn_perm(fe_u(s1), fe_u(s0), 0x07060302);
}

// ----------------------- K1: fused q/k/v (one x pass) -----------------------
// grid 257 x 512thr: blocks 0..255 = (b, frow); block 256 packs Wo.
// 8 waves: wv = (h: cell-half, rg: 12-row group). lane = (cell-in-half, col).
// Thread computes its 12 rows at the 2 spatial positions of its column;
// 2x2 pool = in-thread row-max + one shfl_xor(1).
__global__ void __launch_bounds__(512) k_qkv(const float* __restrict__ x,
                                             const float* __restrict__ Wq,
                                             const float* __restrict__ Wk,
                                             const float* __restrict__ Wv,
                                             const float* __restrict__ Wo,
                                             unsigned short* __restrict__ Qp,
                                             unsigned short* __restrict__ KpB,
                                             float* __restrict__ Vp,
                                             unsigned short* __restrict__ Wop) {
  if (blockIdx.x == 256) {                         // Wo -> bf16, pi on c-cols
    for (int i = threadIdx.x; i < 2048; i += 512) {
      int c = i & 31;
      Wop[i] = f2bf(Wo[(i & ~31) | (c & 16) | pi16(c & 15)]);
    }
    return;
  }
  __shared__ float wst[64][48];                    // [c][row]: q 0-7, k 8-15, v 16-47
  __shared__ float xs[16][256];                    // c-chunk x row-pair strip
  int t = threadIdx.x;
  for (int i = t; i < 512; i += 512) {
    wst[i & 63][i >> 6] = Wq[i];
    wst[i & 63][8 + (i >> 6)] = Wk[i];
  }
  for (int i = t; i < 2048; i += 512) wst[i & 63][16 + (i >> 6)] = Wv[i];
  int b = blockIdx.x >> 6, frow = blockIdx.x & 63;
  int wvx = t >> 6, rg = wvx & 3, h = wvx >> 2;
  int lane = t & 63, c2 = lane >> 1, cpos = lane & 1;
  int cell = h * 32 + c2, col = h * 64 + lane;     // col == 2*cell + cpos
  const float* xb = x + (size_t)b * (64 * 16384) + frow * 256;
  float acc[12][2];
#pragma unroll
  for (int j = 0; j < 12; ++j) { acc[j][0] = 0.f; acc[j][1] = 0.f; }
  int cl = t >> 5, seg = t & 31;                   // staging role
  for (int cc = 0; cc < 4; ++cc) {
    __syncthreads();                               // xs free (covers wst on cc=0)
    const float4* src =
        reinterpret_cast<const float4*>(xb + (size_t)(cc * 16 + cl) * 16384 + seg * 8);
    float4* dst = reinterpret_cast<float4*>(&xs[cl][seg * 8]);
    dst[0] = src[0]; dst[1] = src[1];
    __syncthreads();
#pragma unroll
    for (int c16 = 0; c16 < 16; ++c16) {
      int c = cc * 16 + c16;
      float xa = xs[c16][col], xo = xs[c16][128 + col];
      float4 w0 = *reinterpret_cast<const float4*>(&wst[c][12 * rg]);
      float4 w1 = *reinterpret_cast<const float4*>(&wst[c][12 * rg + 4]);
      float4 w2 = *reinterpret_cast<const float4*>(&wst[c][12 * rg + 8]);
      float wj[12] = {w0.x, w0.y, w0.z, w0.w, w1.x, w1.y, w1.z, w1.w,
                      w2.x, w2.y, w2.z, w2.w};
#pragma unroll
      for (int j = 0; j < 12; ++j) {
        acc[j][0] = fmaf(wj[j], xa, acc[j][0]);
        acc[j][1] = fmaf(wj[j], xo, acc[j][1]);
      }
    }
  }
  float pm[12];
#pragma unroll
  for (int j = 0; j < 12; ++j) {
    pm[j] = fmaxf(acc[j][0], acc[j][1]);
    pm[j] = fmaxf(pm[j], __shfl_xor(pm[j], 1));
  }
  size_t idx = (size_t)b * 4096 + frow * 64 + cell;
  uint4 z4; z4.x = z4.y = z4.z = z4.w = 0u;
  if (rg == 0) {
    // q rows 0-7 at this thread's 2 positions
#pragma unroll
    for (int p = 0; p < 2; ++p) {
      int kpos = frow * 256 + p * 128 + col;
      uint4 qa;
      qa.x = pk2(f2bf(acc[0][p]), f2bf(acc[1][p]));
      qa.y = pk2(f2bf(acc[2][p]), f2bf(acc[3][p]));
      qa.z = pk2(f2bf(acc[4][p]), f2bf(acc[5][p]));
      qa.w = pk2(f2bf(acc[6][p]), f2bf(acc[7][p]));
      uint4* qdst = reinterpret_cast<uint4*>(Qp + ((size_t)b * 16384 + kpos) * 16);
      qdst[0] = qa; qdst[1] = z4;
    }
    if (cpos == 0) {                               // k chans 0-3 (rows 8-11)
      uint2 kw;
      kw.x = pk2(f2bf(pm[8] * LOG2E), f2bf(pm[9] * LOG2E));
      kw.y = pk2(f2bf(pm[10] * LOG2E), f2bf(pm[11] * LOG2E));
      *reinterpret_cast<uint2*>(KpB + idx * 16) = kw;
    }
  } else if (rg == 1) {
    if (cpos == 0) {                               // k chans 4-7 + pad, v 0-7
      uint2 kw;
      kw.x = pk2(f2bf(pm[0] * LOG2E), f2bf(pm[1] * LOG2E));
      kw.y = pk2(f2bf(pm[2] * LOG2E), f2bf(pm[3] * LOG2E));
      *reinterpret_cast<uint2*>(KpB + idx * 16 + 4) = kw;
      *reinterpret_cast<uint4*>(KpB + idx * 16 + 8) = z4;
      float* vd = Vp + idx * 32;
      *reinterpret_cast<float4*>(vd) = make_float4(pm[4], pm[5], pm[6], pm[7]);
      *reinterpret_cast<float4*>(vd + 4) = make_float4(pm[8], pm[9], pm[10], pm[11]);
    }
  } else if (cpos == 0) {                          // rg2: v 8-19; rg3: v 20-31
    float* vd = Vp + idx * 32 + (rg == 2 ? 8 : 20);
#pragma unroll
    for (int j4 = 0; j4 < 3; ++j4)
      *reinterpret_cast<float4*>(vd + 4 * j4) =
          make_float4(pm[4 * j4], pm[4 * j4 + 1], pm[4 * j4 + 2], pm[4 * j4 + 3]);
  }
}

// --------------------- K2: partial l = sum exp2(S2) -------------------------
// grid (b4 x fg128 x kh2) = 1024 blocks x 1024 thr (16 waves); each wave owns
// a 512-k slice of its k-half. FB=1 keeps VGPR <= 64 (8 waves/SIMD).
__global__ void __launch_bounds__(1024) k_lsum(const unsigned short* __restrict__ Qp,
                                               const unsigned short* __restrict__ KpB,
                                               float* __restrict__ Lpart) {
  int b = blockIdx.x >> 8, r = blockIdx.x & 255;
  int fg = r >> 1, kh = r & 1;
  int wv = threadIdx.x >> 6, lane = threadIdx.x & 63;
  int half = lane >> 5, l31 = lane & 31;
  bf8_t A = *reinterpret_cast<const bf8_t*>(
      KpB + ((size_t)(b * 4096 + fg * 32 + l31)) * 16 + half * 8);
  const unsigned short* qbase = Qp + ((size_t)b * 16384) * 16 + half * 8;
  fx16 z;
#pragma unroll
  for (int i = 0; i < 16; ++i) z[i] = 0.f;
  float l[16];
#pragma unroll
  for (int i = 0; i < 16; ++i) l[i] = 0.f;
  int t0 = kh * 256 + wv * 16;                     // chunk units of 32 k
  bf8_t B = *reinterpret_cast<const bf8_t*>(qbase + (size_t)(t0 * 32 + l31) * 16);
  for (int i = 0; i < 16; ++i) {
    int tn = t0 + ((i + 1) & 15);
    bf8_t nB = *reinterpret_cast<const bf8_t*>(qbase + (size_t)(tn * 32 + l31) * 16);
    fx16 s = __builtin_amdgcn_mfma_f32_32x32x16_bf16(A, B, z, 0, 0, 0);
#pragma unroll
    for (int r0 = 0; r0 < 16; ++r0) l[r0] += fe_f(s[r0]);
    B = nB;
  }
#pragma unroll
  for (int r0 = 0; r0 < 16; ++r0)
    for (int d = 1; d < 32; d <<= 1) l[r0] += __shfl_xor(l[r0], d);
  __shared__ float sl[16][32];
  if (l31 == 0) {
#pragma unroll
    for (int r0 = 0; r0 < 16; ++r0) {
      int row = (r0 & 3) + 8 * (r0 >> 2) + 4 * half;
      sl[wv][row] = l[r0];
    }
  }
  __syncthreads();
  if (threadIdx.x < 32) {
    float L = 0.f;
#pragma unroll
    for (int w2 = 0; w2 < 16; ++w2) L += sl[w2][threadIdx.x];
    Lpart[(size_t)kh * 16384 + b * 4096 + fg * 32 + threadIdx.x] = L;
  }
}

// ------------------------------ K3: pack -----------------------------------
// Vpp[b][c][f'] bf16 = Vp[b][pi(f)][c] / (Lpart0+Lpart1)[pi(f)].
__global__ void __launch_bounds__(256) k_pack(const float* __restrict__ Vp,
                                              const float* __restrict__ Lpart,
                                              unsigned short* __restrict__ Vpp) {
  int b = blockIdx.x >> 4, f0 = (blockIdx.x & 15) * 256;
  __shared__ unsigned short T[32][264];            // +8 pad, rows 16B-aligned
  int t = threadIdx.x;
  size_t li = (size_t)b * 4096 + f0 + t;
  float rl = 1.0f / (Lpart[li] + Lpart[16384 + li]);
  const float* vp = Vp + li * 32;
  int fl = (t & ~15) | pi16(t & 15);               // destination column (involution)
  for (int c = 0; c < 32; ++c) T[c][fl] = f2bf(vp[c] * rl);
  __syncthreads();
  for (int u = t; u < 1024; u += 256) {            // 32 rows x 32 uint4
    int row = u >> 5, e0 = (u & 31) * 8;
    uint4 val = *reinterpret_cast<const uint4*>(&T[row][e0]);
    *reinterpret_cast<uint4*>(Vpp + ((size_t)b * 32 + row) * 4096 + f0 + e0) = val;
  }
}

// ------------------------- K4: attention + project --------------------------
// 512 thr (8 waves) per 64-k pair; waves split f 8-ways, KB=2 per wave.
// P = fast-exp2 -> bf16 via v_perm (no transcendentals). Two-phase fp32 LDS
// reduction; waves 0-3 do the (kt, ot) Wo epilogue with early x prefetch.
__global__ void __launch_bounds__(512) k_attn(const unsigned short* __restrict__ Qp,
                                              const unsigned short* __restrict__ KpB,
                                              const unsigned short* __restrict__ Vpp,
                                              const unsigned short* __restrict__ Wop,
                                              const float* __restrict__ x,
                                              const float* __restrict__ gamma,
                                              float* __restrict__ out) {
  int b = blockIdx.x >> 8, kp = blockIdx.x & 255;
  int wv = threadIdx.x >> 6, lane = threadIdx.x & 63;
  int half = lane >> 5, l31 = lane & 31;
  int kbase = kp * 64;
  const unsigned short* qb = Qp + ((size_t)b * 16384 + kbase + l31) * 16 + half * 8;
  bf8_t Bq0 = *reinterpret_cast<const bf8_t*>(qb);
  bf8_t Bq1 = *reinterpret_cast<const bf8_t*>(qb + 32 * 16);
  fx16 z;
#pragma unroll
  for (int i = 0; i < 16; ++i) z[i] = 0.f;
  fx16 acc0 = z, acc1 = z;
  const unsigned short* kpB = KpB + ((size_t)b * 4096 + l31) * 16 + half * 8;
  const unsigned short* vpB = Vpp + ((size_t)(b * 32 + l31)) * 4096 + half * 8;
  int c0 = wv * 16;                                // wave's first f-chunk
  int f0 = c0 * 32;
  bf8_t Ak  = *reinterpret_cast<const bf8_t*>(kpB + (size_t)f0 * 16);
  bf8_t Av0 = *reinterpret_cast<const bf8_t*>(vpB + f0);
  bf8_t Av1 = *reinterpret_cast<const bf8_t*>(vpB + f0 + 16);
  for (int fc = 0; fc < 16; ++fc) {
    int f1 = (c0 + ((fc + 1) & 15)) * 32;          // wraps within wave's range
    bf8_t nAk  = *reinterpret_cast<const bf8_t*>(kpB + (size_t)f1 * 16);
    bf8_t nAv0 = *reinterpret_cast<const bf8_t*>(vpB + f1);
    bf8_t nAv1 = *reinterpret_cast<const bf8_t*>(vpB + f1 + 16);
    fx16 s0 = __builtin_amdgcn_mfma_f32_32x32x16_bf16(Ak, Bq0, z, 0, 0, 0);
    fx16 s1 = __builtin_amdgcn_mfma_f32_32x32x16_bf16(Ak, Bq1, z, 0, 0, 0);
    uint4 u00, u01, u10, u11;
    u00.x = fe_pk(s0[0], s0[1]);   u00.y = fe_pk(s0[2], s0[3]);
    u00.z = fe_pk(s0[4], s0[5]);   u00.w = fe_pk(s0[6], s0[7]);
    u01.x = fe_pk(s0[8], s0[9]);   u01.y = fe_pk(s0[10], s0[11]);
    u01.z = fe_pk(s0[12], s0[13]); u01.w = fe_pk(s0[14], s0[15]);
    u10.x = fe_pk(s1[0], s1[1]);   u10.y = fe_pk(s1[2], s1[3]);
    u10.z = fe_pk(s1[4], s1[5]);   u10.w = fe_pk(s1[6], s1[7]);
    u11.x = fe_pk(s1[8], s1[9]);   u11.y = fe_pk(s1[10], s1[11]);
    u11.z = fe_pk(s1[12], s1[13]); u11.w = fe_pk(s1[14], s1[15]);
    bf8_t P00 = __builtin_bit_cast(bf8_t, u00);
    bf8_t P01 = __builtin_bit_cast(bf8_t, u01);
    bf8_t P10 = __builtin_bit_cast(bf8_t, u10);
    bf8_t P11 = __builtin_bit_cast(bf8_t, u11);
    acc0 = __builtin_amdgcn_mfma_f32_32x32x16_bf16(Av0, P00, acc0, 0, 0, 0);
    acc1 = __builtin_amdgcn_mfma_f32_32x32x16_bf16(Av0, P10, acc1, 0, 0, 0);
    acc0 = __builtin_amdgcn_mfma_f32_32x32x16_bf16(Av1, P01, acc0, 0, 0, 0);
    acc1 = __builtin_amdgcn_mfma_f32_32x32x16_bf16(Av1, P11, acc1, 0, 0, 0);
    Ak = nAk; Av0 = nAv0; Av1 = nAv1;
  }
  // two-phase reduction: waves 4-7 deposit, waves 0-3 merge + epilogue.
  __shared__ float sacc[4][2][4][64][4];
  if (wv >= 4) {
    int s = wv - 4;
#pragma unroll
    for (int j4 = 0; j4 < 4; ++j4) {
      *reinterpret_cast<float4*>(&sacc[s][0][j4][lane][0]) =
          make_float4(acc0[4 * j4], acc0[4 * j4 + 1], acc0[4 * j4 + 2], acc0[4 * j4 + 3]);
      *reinterpret_cast<float4*>(&sacc[s][1][j4][lane][0]) =
          make_float4(acc1[4 * j4], acc1[4 * j4 + 1], acc1[4 * j4 + 2], acc1[4 * j4 + 3]);
    }
  }
  __syncthreads();
  if (wv >= 4) return;
  int kt = wv & 1, ot = wv >> 1;
  // early x prefetch (HBM) — consumed at the very end
  int k = kbase + kt * 32 + l31;
  const float* xp = x + (size_t)b * 64 * 16384 + k;
  float xv[16];
#pragma unroll
  for (int r0 = 0; r0 < 16; ++r0) {
    int row = (r0 & 3) + 8 * (r0 >> 2) + 4 * half + ot * 32;
    xv[r0] = xp[(size_t)row * 16384];
  }
#pragma unroll
  for (int j4 = 0; j4 < 4; ++j4) {
    float4 p0 = *reinterpret_cast<const float4*>(&sacc[wv][0][j4][lane][0]);
    float4 p1 = *reinterpret_cast<const float4*>(&sacc[wv][1][j4][lane][0]);
    p0.x += acc0[4 * j4]; p0.y += acc0[4 * j4 + 1];
    p0.z += acc0[4 * j4 + 2]; p0.w += acc0[4 * j4 + 3];
    p1.x += acc1[4 * j4]; p1.y += acc1[4 * j4 + 1];
    p1.z += acc1[4 * j4 + 2]; p1.w += acc1[4 * j4 + 3];
    *reinterpret_cast<float4*>(&sacc[wv][0][j4][lane][0]) = p0;
    *reinterpret_cast<float4*>(&sacc[wv][1][j4][lane][0]) = p1;
  }
  __syncthreads();
  fx16 tot;
#pragma unroll
  for (int j4 = 0; j4 < 4; ++j4) {
    float4 a0 = *reinterpret_cast<const float4*>(&sacc[0][kt][j4][lane][0]);
    float4 a1 = *reinterpret_cast<const float4*>(&sacc[1][kt][j4][lane][0]);
    float4 a2 = *reinterpret_cast<const float4*>(&sacc[2][kt][j4][lane][0]);
    float4 a3 = *reinterpret_cast<const float4*>(&sacc[3][kt][j4][lane][0]);
    tot[4 * j4]     = (a0.x + a1.x) + (a2.x + a3.x);
    tot[4 * j4 + 1] = (a0.y + a1.y) + (a2.y + a3.y);
    tot[4 * j4 + 2] = (a0.z + a1.z) + (a2.z + a3.z);
    tot[4 * j4 + 3] = (a0.w + a1.w) + (a2.w + a3.w);
  }
  bf8_t Ob0, Ob1;
#pragma unroll
  for (int j = 0; j < 8; ++j) { Ob0[j] = (__bf16)tot[j]; Ob1[j] = (__bf16)tot[8 + j]; }
  const unsigned short* wb = Wop + (ot * 32 + l31) * 32 + half * 8;
  bf8_t Aw0 = *reinterpret_cast<const bf8_t*>(wb);
  bf8_t Aw1 = *reinterpret_cast<const bf8_t*>(wb + 16);
  fx16 y = __builtin_amdgcn_mfma_f32_32x32x16_bf16(Aw0, Ob0, z, 0, 0, 0);
  y = __builtin_amdgcn_mfma_f32_32x32x16_bf16(Aw1, Ob1, y, 0, 0, 0);
  float g = gamma[0];
  float* op = out + (size_t)b * 64 * 16384 + k;
#pragma unroll
  for (int r0 = 0; r0 < 16; ++r0) {
    int row = (r0 & 3) + 8 * (r0 >> 2) + 4 * half + ot * 32;
    op[(size_t)row * 16384] = fmaf(g, y[r0], xv[r0]);
  }
}

// ---------------------------------------------------------------------------
extern "C" void kernel_launch(void* const* d_in, const int* in_sizes, int n_in,
                              void* d_out, int out_size, void* d_ws, size_t ws_size,
                              hipStream_t stream) {
  const float* x     = (const float*)d_in[0];
  const float* Wq    = (const float*)d_in[1];
  const float* Wk    = (const float*)d_in[2];
  const float* Wv    = (const float*)d_in[3];
  const float* Wo    = (const float*)d_in[4];
  const float* gamma = (const float*)d_in[5];
  float* out = (float*)d_out;
  char* ws = (char*)d_ws;
  // workspace layout (bytes)
  unsigned short* Qp    = (unsigned short*)(ws + 0);        // 2 MB
  unsigned short* KpB   = (unsigned short*)(ws + 2097152);  // 512 KB
  float*          Vp    = (float*)(ws + 2621440);           // 2 MB
  unsigned short* Vpp   = (unsigned short*)(ws + 4718592);  // 1 MB
  float*          Lpart = (float*)(ws + 5767168);           // 128 KB (2 planes)
  unsigned short* Wop   = (unsigned short*)(ws + 5898240);  // 4 KB

  k_qkv <<<dim3(257),  dim3(512),  0, stream>>>(x, Wq, Wk, Wv, Wo, Qp, KpB, Vp, Wop);
  k_lsum<<<dim3(1024), dim3(1024), 0, stream>>>(Qp, KpB, Lpart);
  k_pack<<<dim3(64),   dim3(256),  0, stream>>>(Vp, Lpart, Vpp);
  k_attn<<<dim3(1024), dim3(512),  0, stream>>>(Qp, KpB, Vpp, Wop, x, gamma, out);
}